// Round 1
// baseline (15345.917 us; speedup 1.0000x reference)
//
#include <hip/hip_runtime.h>
#include <stdint.h>

#define LSEQ 1024
#define NB   64
#define DM   1024
#define FOURD 4096
#define KTOT 2048
#define WC   128    // WGs per batch-row group (barrier group size)

typedef float f32x4 __attribute__((ext_vector_type(4)));
typedef short short8_t __attribute__((ext_vector_type(8)));
typedef __bf16 bf16x8 __attribute__((ext_vector_type(8)));

__device__ __forceinline__ unsigned short f2bf(float f) {
    unsigned int u = __builtin_bit_cast(unsigned int, f);
    u += 0x7fffu + ((u >> 16) & 1u);   // RNE
    return (unsigned short)(u >> 16);
}

__device__ __forceinline__ f32x4 mfma16(short8_t a, short8_t b, f32x4 c) {
    return __builtin_amdgcn_mfma_f32_16x16x32_bf16(
        __builtin_bit_cast(bf16x8, a), __builtin_bit_cast(bf16x8, b), c, 0, 0, 0);
}

__global__ void init_ws_kernel(unsigned int* __restrict__ p, int n) {
    int i = blockIdx.x * blockDim.x + threadIdx.x;
    int stride = gridDim.x * blockDim.x;
    for (; i < n; i += stride) p[i] = 0u;
}

__global__ void convert_x_kernel(const float4* __restrict__ src, uint4* __restrict__ dst) {
    size_t i = (size_t)blockIdx.x * blockDim.x + threadIdx.x;  // 8 elems per thread
    float4 a = src[2 * i];
    float4 b = src[2 * i + 1];
    uint4 r;
    r.x = (unsigned)f2bf(a.x) | ((unsigned)f2bf(a.y) << 16);
    r.y = (unsigned)f2bf(a.z) | ((unsigned)f2bf(a.w) << 16);
    r.z = (unsigned)f2bf(b.x) | ((unsigned)f2bf(b.y) << 16);
    r.w = (unsigned)f2bf(b.z) | ((unsigned)f2bf(b.w) << 16);
    dst[i] = r;
}

// Persistent LSTM kernel.
// Grid = 256 WGs x 256 threads. LDS 132 KiB forces 1 WG/CU -> all 256 co-resident.
// WG (g,ug): batch rows [32g,32g+32), hidden units [8ug, 8ug+8) (=32 gate cols).
// Local col c (0..31): gate q=c>>3, unit u=c&7 -> global col q*1024 + 8*ug + u.
// Wlds[c][k] bf16, k in [0,2048) = [Wi;Wh], byte-offset XOR-swizzled by ((c&7)<<4).
template <int XB>
__global__ __launch_bounds__(256)
void lstm_kernel(const float* __restrict__ x,
                 const float* __restrict__ Wi,
                 const float* __restrict__ Wh,
                 const float* __restrict__ bias,
                 const unsigned short* __restrict__ xb,
                 unsigned short* __restrict__ hbuf,   // [2][64][1024] bf16
                 unsigned int* __restrict__ ctr,      // 2 counters, 256B apart
                 float* __restrict__ out)             // [L][N][D] fp32
{
    __shared__ short Wlds[32 * KTOT];   // 128 KiB
    __shared__ float ylds[32 * 33];     // padded stride to kill bank conflicts
    __shared__ float blds[32];

    const int tid  = threadIdx.x;
    const int wgid = blockIdx.x;
    const int g    = wgid >> 7;     // row group 0/1
    const int ug   = wgid & 127;    // unit group
    const int U0   = ug << 3;
    const int rowbase = g << 5;

    // ---- one-time: stage weight slice into LDS as bf16 ----
    {
        const int c    = tid & 31;
        const int gcol = ((c >> 3) << 10) + U0 + (c & 7);
        const int swz  = (c & 7) << 4;
        char* wrow = (char*)Wlds + c * (KTOT * 2);
        #pragma unroll 8
        for (int k = tid >> 5; k < 1024; k += 8)
            *(unsigned short*)(wrow + ((k * 2) ^ swz)) = f2bf(Wi[(size_t)k * FOURD + gcol]);
        #pragma unroll 8
        for (int k = tid >> 5; k < 1024; k += 8)
            *(unsigned short*)(wrow + (((k + 1024) * 2) ^ swz)) = f2bf(Wh[(size_t)k * FOURD + gcol]);
        if (tid < 32) blds[tid] = bias[((tid >> 3) << 10) + U0 + (tid & 7)];
    }
    __syncthreads();

    // wave -> 16x16 output tile: rt = row tile (2), ct = col tile (2)
    const int lane = tid & 63;
    const int wv   = tid >> 6;
    const int rt   = wv >> 1;
    const int ct   = wv & 1;
    const int arow = rowbase + (rt << 4) + (lane & 15);  // batch row for A frag
    const int kseg = (lane >> 4) << 3;                   // k offset within 32-step
    const int c0   = (ct << 4) + (lane & 15);            // local col for B frag
    const char* brow = (const char*)Wlds + c0 * (KTOT * 2);
    const int swzB = (c0 & 7) << 4;

    // epilogue mapping: one (row, unit) per thread; c-state lives in a register
    const int er = tid >> 3;
    const int eu = tid & 7;
    const float bI = blds[eu], bF = blds[8 + eu], bG = blds[16 + eu], bO = blds[24 + eu];
    float cstate = 0.0f;
    unsigned int* myctr = ctr + (g << 6);
    unsigned int target = 0;

    for (int t = 0; t < LSEQ; ++t) {
        f32x4 acc0 = {0.f, 0.f, 0.f, 0.f};
        f32x4 acc1 = {0.f, 0.f, 0.f, 0.f};

        // ---- x-part (k 0..1023): no carry dependency, runs before barrier ----
        if (XB) {
            const unsigned short* ap = xb + ((size_t)t * NB + arow) * DM + kseg;
            #pragma unroll 8
            for (int kk = 0; kk < 32; ++kk) {
                short8_t a = *(const short8_t*)(ap + kk * 32);
                short8_t b = *(const short8_t*)(brow + (((kk * 32 + kseg) * 2) ^ swzB));
                if (kk & 1) acc1 = mfma16(a, b, acc1);
                else        acc0 = mfma16(a, b, acc0);
            }
        } else {
            const float* ap = x + ((size_t)t * NB + arow) * DM + kseg;
            #pragma unroll 4
            for (int kk = 0; kk < 32; ++kk) {
                float4 lo = *(const float4*)(ap + kk * 32);
                float4 hi = *(const float4*)(ap + kk * 32 + 4);
                short8_t a;
                a[0] = (short)f2bf(lo.x); a[1] = (short)f2bf(lo.y);
                a[2] = (short)f2bf(lo.z); a[3] = (short)f2bf(lo.w);
                a[4] = (short)f2bf(hi.x); a[5] = (short)f2bf(hi.y);
                a[6] = (short)f2bf(hi.z); a[7] = (short)f2bf(hi.w);
                short8_t b = *(const short8_t*)(brow + (((kk * 32 + kseg) * 2) ^ swzB));
                if (kk & 1) acc1 = mfma16(a, b, acc1);
                else        acc0 = mfma16(a, b, acc0);
            }
        }

        // ---- wait for h[t-1] from this row group (128 arrivals per step) ----
        if (tid == 0) {
            while (__hip_atomic_load(myctr, __ATOMIC_RELAXED, __HIP_MEMORY_SCOPE_AGENT) < target)
                __builtin_amdgcn_s_sleep(1);
            __builtin_amdgcn_fence(__ATOMIC_ACQUIRE, "agent");
        }
        __syncthreads();

        // ---- h-part (k 1024..2047) ----
        {
            const unsigned short* ap =
                hbuf + (size_t)((t & 1) ^ 1) * (NB * DM) + (size_t)arow * DM + kseg;
            #pragma unroll 8
            for (int kk = 0; kk < 32; ++kk) {
                short8_t a = *(const short8_t*)(ap + kk * 32);
                short8_t b = *(const short8_t*)(brow + (((kk * 32 + kseg + 1024) * 2) ^ swzB));
                if (kk & 1) acc1 = mfma16(a, b, acc1);
                else        acc0 = mfma16(a, b, acc0);
            }
        }

        // ---- y tile -> LDS (C/D layout: col=lane&15, row=(lane>>4)*4+j) ----
        {
            f32x4 acc = acc0 + acc1;
            const int r0 = (rt << 4) + ((lane >> 4) << 2);
            #pragma unroll
            for (int j = 0; j < 4; ++j) ylds[(r0 + j) * 33 + c0] = acc[j];
        }
        __syncthreads();

        // ---- gate epilogue ----
        {
            const float* yr = ylds + er * 33;
            float vi = yr[eu]      + bI;
            float vf = yr[8 + eu]  + bF;
            float vg = yr[16 + eu] + bG;
            float vo = yr[24 + eu] + bO;
            float gi = 1.0f / (1.0f + __expf(-vi));
            float gf = 1.0f / (1.0f + __expf(-vf));
            float gg = 1.0f - 2.0f / (__expf(2.0f * vg) + 1.0f);
            float go = 1.0f / (1.0f + __expf(-vo));
            cstate = gf * cstate + gi * gg;
            float hv = go * (1.0f - 2.0f / (__expf(2.0f * cstate) + 1.0f));
            const int n = rowbase + er;
            const int d = U0 + eu;
            out[((size_t)t * NB + n) * DM + d] = hv;
            hbuf[(size_t)(t & 1) * (NB * DM) + (size_t)n * DM + d] = f2bf(hv);
        }
        __syncthreads();   // drains all stores (vmcnt 0) before release

        if (tid == 0) {
            __builtin_amdgcn_fence(__ATOMIC_RELEASE, "agent");
            __hip_atomic_fetch_add(myctr, 1u, __ATOMIC_RELAXED, __HIP_MEMORY_SCOPE_AGENT);
        }
        target += WC;
    }
}

extern "C" void kernel_launch(void* const* d_in, const int* in_sizes, int n_in,
                              void* d_out, int out_size, void* d_ws, size_t ws_size,
                              hipStream_t stream) {
    (void)in_sizes; (void)n_in; (void)out_size;
    const float* x  = (const float*)d_in[0];
    const float* Wi = (const float*)d_in[1];
    const float* Wh = (const float*)d_in[2];
    const float* b  = (const float*)d_in[3];
    float* out = (float*)d_out;

    char* ws = (char*)d_ws;
    unsigned int*   ctr  = (unsigned int*)ws;                 // 4 KiB (2 counters, 256B apart)
    unsigned short* hbuf = (unsigned short*)(ws + 4096);      // 256 KiB double-buffered h (bf16)
    unsigned short* xb   = (unsigned short*)(ws + 266240);    // 128 MiB bf16 x (optional)

    // zero barrier counters + h buffers every call (ws is poisoned once, never restored)
    init_ws_kernel<<<64, 256, 0, stream>>>((unsigned int*)ws, 266240 / 4);

    const bool use_xb = ws_size >= 266240ull + 134217728ull;
    if (use_xb) {
        convert_x_kernel<<<32768, 256, 0, stream>>>((const float4*)x, (uint4*)xb);
        lstm_kernel<1><<<256, 256, 0, stream>>>(x, Wi, Wh, b, xb, hbuf, ctr, out);
    } else {
        lstm_kernel<0><<<256, 256, 0, stream>>>(x, Wi, Wh, b, xb, hbuf, ctr, out);
    }
}

// Round 2
// 10919.352 us; speedup vs baseline: 1.4054x; 1.4054x over previous
//
#include <hip/hip_runtime.h>
#include <stdint.h>

#define LSEQ 1024
#define NB   64
#define DM   1024
#define FOURD 4096

typedef float f32x4 __attribute__((ext_vector_type(4)));
typedef short short8_t __attribute__((ext_vector_type(8)));
typedef __bf16 bf16x8 __attribute__((ext_vector_type(8)));

__device__ __forceinline__ unsigned short f2bf(float f) {
    unsigned int u = __builtin_bit_cast(unsigned int, f);
    u += 0x7fffu + ((u >> 16) & 1u);   // RNE
    return (unsigned short)(u >> 16);
}

__device__ __forceinline__ f32x4 mfma16(short8_t a, short8_t b, f32x4 c) {
    return __builtin_amdgcn_mfma_f32_16x16x32_bf16(
        __builtin_bit_cast(bf16x8, a), __builtin_bit_cast(bf16x8, b), c, 0, 0, 0);
}

__global__ void init_ws_kernel(unsigned int* __restrict__ p, int n) {
    int i = blockIdx.x * blockDim.x + threadIdx.x;
    int stride = gridDim.x * blockDim.x;
    for (; i < n; i += stride) p[i] = 0u;
}

__global__ void convert_x_kernel(const float4* __restrict__ src, uint4* __restrict__ dst) {
    size_t i = (size_t)blockIdx.x * blockDim.x + threadIdx.x;  // 8 elems per thread
    float4 a = src[2 * i];
    float4 b = src[2 * i + 1];
    uint4 r;
    r.x = (unsigned)f2bf(a.x) | ((unsigned)f2bf(a.y) << 16);
    r.y = (unsigned)f2bf(a.z) | ((unsigned)f2bf(a.w) << 16);
    r.z = (unsigned)f2bf(b.x) | ((unsigned)f2bf(b.y) << 16);
    r.w = (unsigned)f2bf(b.z) | ((unsigned)f2bf(b.w) << 16);
    dst[i] = r;
}

// ---- h-part pipelined coherent loads (bypass L1/L2, counted vmcnt) ----
#define HL(arr, i, OFFS)                                                        \
    asm volatile("global_load_dwordx4 %0, %1, off offset:" OFFS " sc0 sc1"      \
                 : "=v"(arr[i]) : "v"(hap) : "memory")
#define WAITV(NSTR)                                          \
    asm volatile("s_waitcnt vmcnt(" NSTR ")" ::: "memory");  \
    __builtin_amdgcn_sched_barrier(0)
#define HM(arr, i, kk) {                                        \
    short8_t b = *(const short8_t*)(bph + (kk) * 1024);         \
    if ((kk) & 1) acc1 = mfma16(arr[i], b, acc1);               \
    else          acc0 = mfma16(arr[i], b, acc0); }

// Persistent LSTM kernel.
// Grid = 256 WGs x 256 threads, 1 WG/CU (LDS-forced) -> all co-resident.
// WG (g,ug): batch rows [32g,32g+32), hidden units [8ug,8ug+8) (=32 gate cols).
// Weights in LDS, bf16, layout [half][ct][kk][lane][8] -> conflict-free ds_read_b128.
// Cross-WG h exchange: per-access coherent ops through L3 (no fences, no atomics
// contention): stores = relaxed agent atomic u32 (write-through), loads = asm
// global_load sc0 sc1. Arrival via per-WG flag array, wave-0 poll.
template <int XB>
__global__ __launch_bounds__(256)
void lstm_kernel(const float* __restrict__ x,
                 const float* __restrict__ Wi,
                 const float* __restrict__ Wh,
                 const float* __restrict__ bias,
                 const unsigned short* __restrict__ xb,
                 unsigned short* __restrict__ hbuf,   // [2][64][1024] bf16
                 unsigned int* __restrict__ flags,    // [2][128] step counters
                 float* __restrict__ out)             // [L][N][D] fp32
{
    __shared__ short Wlds[65536];       // 128 KiB: [H][ct][kk][lane][8]
    __shared__ float ylds[32 * 33];     // padded
    __shared__ float blds[32];

    const int tid  = threadIdx.x;
    const int wgid = blockIdx.x;
    const int g    = wgid >> 7;     // row group 0/1
    const int ug   = wgid & 127;    // unit group
    const int U0   = ug << 3;
    const int rowbase = g << 5;

    // ---- one-time: stage weight slice into LDS (frag-ordered, conflict-free) ----
    {
        const int c    = tid & 31;
        const int ct_  = c >> 4;
        const int lb   = c & 15;
        const int gcol = ((c >> 3) << 10) + U0 + (c & 7);
        for (int k = tid >> 5; k < 1024; k += 8) {
            const int lane_ = lb | (((k >> 3) & 3) << 4);
            const int sidx  = (ct_ * 32 + (k >> 5)) * 512 + lane_ * 8 + (k & 7);
            Wlds[sidx]         = (short)f2bf(Wi[(size_t)k * FOURD + gcol]);
            Wlds[sidx + 32768] = (short)f2bf(Wh[(size_t)k * FOURD + gcol]);
        }
        if (tid < 32) blds[tid] = bias[((tid >> 3) << 10) + U0 + (tid & 7)];
    }
    __syncthreads();

    // wave -> 16x16 output tile: rt = row tile (2), ct = col tile (2)
    const int lane = tid & 63;
    const int wv   = tid >> 6;
    const int rt   = wv >> 1;
    const int ct   = wv & 1;
    const int arow = rowbase + (rt << 4) + (lane & 15);  // batch row for A frag
    const int kseg = (lane >> 4) << 3;                   // k offset within 32-step
    const char* bpx = (const char*)Wlds + ct * 32768 + lane * 16;           // x-half B
    const char* bph = (const char*)Wlds + 65536 + ct * 32768 + lane * 16;   // h-half B

    // epilogue mapping: one (row, unit) per thread; c-state lives in a register
    const int er = tid >> 3;
    const int eu = tid & 7;
    const float bI = blds[eu], bF = blds[8 + eu], bG = blds[16 + eu], bO = blds[24 + eu];
    float cstate = 0.0f;
    unsigned int* gflags = flags + (g << 7);

    for (int t = 0; t < LSEQ; ++t) {
        f32x4 acc0 = {0.f, 0.f, 0.f, 0.f};
        f32x4 acc1 = {0.f, 0.f, 0.f, 0.f};

        // ---- x-part (k 0..1023): no carry dependency, overlaps the wait ----
        if (XB) {
            const unsigned short* ap = xb + ((size_t)t * NB + arow) * DM + kseg;
            #pragma unroll 8
            for (int kk = 0; kk < 32; ++kk) {
                short8_t a = *(const short8_t*)(ap + kk * 32);
                short8_t b = *(const short8_t*)(bpx + kk * 1024);
                if (kk & 1) acc1 = mfma16(a, b, acc1);
                else        acc0 = mfma16(a, b, acc0);
            }
        } else {
            const float* ap = x + ((size_t)t * NB + arow) * DM + kseg;
            #pragma unroll 4
            for (int kk = 0; kk < 32; ++kk) {
                float4 lo = *(const float4*)(ap + kk * 32);
                float4 hi = *(const float4*)(ap + kk * 32 + 4);
                short8_t a;
                a[0] = (short)f2bf(lo.x); a[1] = (short)f2bf(lo.y);
                a[2] = (short)f2bf(lo.z); a[3] = (short)f2bf(lo.w);
                a[4] = (short)f2bf(hi.x); a[5] = (short)f2bf(hi.y);
                a[6] = (short)f2bf(hi.z); a[7] = (short)f2bf(hi.w);
                short8_t b = *(const short8_t*)(bpx + kk * 1024);
                if (kk & 1) acc1 = mfma16(a, b, acc1);
                else        acc0 = mfma16(a, b, acc0);
            }
        }

        // ---- wait: all 128 group WGs posted h[t-1] (distinct flag words) ----
        if (t && wv == 0) {
            const unsigned int* fp = gflags + (lane << 1);
            while (true) {
                unsigned int f0 = __hip_atomic_load(fp,     __ATOMIC_RELAXED, __HIP_MEMORY_SCOPE_AGENT);
                unsigned int f1 = __hip_atomic_load(fp + 1, __ATOMIC_RELAXED, __HIP_MEMORY_SCOPE_AGENT);
                int ok = (f0 >= (unsigned)t) && (f1 >= (unsigned)t);
                if (__all(ok)) break;
                __builtin_amdgcn_s_sleep(1);
            }
        }
        __syncthreads();

        // ---- h-part (k 1024..2047): coherent A loads, 4x8 pipelined chunks ----
        {
            const unsigned short* hap =
                hbuf + (size_t)((t & 1) ^ 1) * (NB * DM) + (size_t)arow * DM + kseg;
            short8_t A0[8], A1[8];
            HL(A0,0,"0");    HL(A0,1,"64");   HL(A0,2,"128");  HL(A0,3,"192");
            HL(A0,4,"256");  HL(A0,5,"320");  HL(A0,6,"384");  HL(A0,7,"448");
            HL(A1,0,"512");  HL(A1,1,"576");  HL(A1,2,"640");  HL(A1,3,"704");
            HL(A1,4,"768");  HL(A1,5,"832");  HL(A1,6,"896");  HL(A1,7,"960");
            WAITV("8");
            HM(A0,0,0)  HM(A0,1,1)  HM(A0,2,2)  HM(A0,3,3)
            HM(A0,4,4)  HM(A0,5,5)  HM(A0,6,6)  HM(A0,7,7)
            HL(A0,0,"1024"); HL(A0,1,"1088"); HL(A0,2,"1152"); HL(A0,3,"1216");
            HL(A0,4,"1280"); HL(A0,5,"1344"); HL(A0,6,"1408"); HL(A0,7,"1472");
            WAITV("8");
            HM(A1,0,8)  HM(A1,1,9)  HM(A1,2,10) HM(A1,3,11)
            HM(A1,4,12) HM(A1,5,13) HM(A1,6,14) HM(A1,7,15)
            HL(A1,0,"1536"); HL(A1,1,"1600"); HL(A1,2,"1664"); HL(A1,3,"1728");
            HL(A1,4,"1792"); HL(A1,5,"1856"); HL(A1,6,"1920"); HL(A1,7,"1984");
            WAITV("8");
            HM(A0,0,16) HM(A0,1,17) HM(A0,2,18) HM(A0,3,19)
            HM(A0,4,20) HM(A0,5,21) HM(A0,6,22) HM(A0,7,23)
            WAITV("0");
            HM(A1,0,24) HM(A1,1,25) HM(A1,2,26) HM(A1,3,27)
            HM(A1,4,28) HM(A1,5,29) HM(A1,6,30) HM(A1,7,31)
        }

        // ---- y tile -> LDS (C/D layout: col=lane&15, row=(lane>>4)*4+j) ----
        {
            f32x4 acc = acc0 + acc1;
            const int r0 = (rt << 4) + ((lane >> 4) << 2);
            const int c0 = (ct << 4) + (lane & 15);
            #pragma unroll
            for (int j = 0; j < 4; ++j) ylds[(r0 + j) * 33 + c0] = acc[j];
        }
        __syncthreads();

        // ---- gate epilogue ----
        {
            const float* yr = ylds + er * 33;
            float vi = yr[eu]      + bI;
            float vf = yr[8 + eu]  + bF;
            float vg = yr[16 + eu] + bG;
            float vo = yr[24 + eu] + bO;
            float gi = 1.0f / (1.0f + __expf(-vi));
            float gf = 1.0f / (1.0f + __expf(-vf));
            float gg = 1.0f - 2.0f / (__expf(2.0f * vg) + 1.0f);
            float go = 1.0f / (1.0f + __expf(-vo));
            cstate = gf * cstate + gi * gg;
            float hv = go * (1.0f - 2.0f / (__expf(2.0f * cstate) + 1.0f));
            float hvn = __shfl_down(hv, 1);
            if ((tid & 1) == 0) {   // eu even: pack (eu, eu+1)
                const int n = rowbase + er;
                const int d = U0 + eu;
                unsigned int hp = (unsigned)f2bf(hv) | ((unsigned)f2bf(hvn) << 16);
                unsigned int* hw = (unsigned int*)(hbuf + (size_t)(t & 1) * (NB * DM)
                                                   + (size_t)n * DM + d);
                __hip_atomic_store(hw, hp, __ATOMIC_RELAXED, __HIP_MEMORY_SCOPE_AGENT);
                *(float2*)(out + ((size_t)t * NB + n) * DM + d) = make_float2(hv, hvn);
            }
        }
        asm volatile("s_waitcnt vmcnt(0)" ::: "memory");   // h stores at L3
        __syncthreads();

        if (tid == 0) {
            __hip_atomic_store(gflags + ug, (unsigned)(t + 1),
                               __ATOMIC_RELAXED, __HIP_MEMORY_SCOPE_AGENT);
            asm volatile("s_waitcnt vmcnt(0)" ::: "memory");   // same-addr order across steps
        }
    }
}

extern "C" void kernel_launch(void* const* d_in, const int* in_sizes, int n_in,
                              void* d_out, int out_size, void* d_ws, size_t ws_size,
                              hipStream_t stream) {
    (void)in_sizes; (void)n_in; (void)out_size;
    const float* x  = (const float*)d_in[0];
    const float* Wi = (const float*)d_in[1];
    const float* Wh = (const float*)d_in[2];
    const float* b  = (const float*)d_in[3];
    float* out = (float*)d_out;

    char* ws = (char*)d_ws;
    unsigned int*   flags = (unsigned int*)ws;                // 1 KiB (2x128 flags)
    unsigned short* hbuf  = (unsigned short*)(ws + 4096);     // 256 KiB double-buffered h
    unsigned short* xb    = (unsigned short*)(ws + 266240);   // 128 MiB bf16 x (optional)

    // zero flags + h buffers every call (ws poisoned once, never restored)
    init_ws_kernel<<<64, 256, 0, stream>>>((unsigned int*)ws, 266240 / 4);

    const bool use_xb = ws_size >= 266240ull + 134217728ull;
    if (use_xb) {
        convert_x_kernel<<<32768, 256, 0, stream>>>((const float4*)x, (uint4*)xb);
        lstm_kernel<1><<<256, 256, 0, stream>>>(x, Wi, Wh, b, xb, hbuf, flags, out);
    } else {
        lstm_kernel<0><<<256, 256, 0, stream>>>(x, Wi, Wh, b, xb, hbuf, flags, out);
    }
}